// Round 1
// baseline (286.014 us; speedup 1.0000x reference)
//
#include <hip/hip_runtime.h>

#define PTOT   1048576
#define NRAYS  8192
#define THRESH 1e-4f

typedef float F2 __attribute__((ext_vector_type(2)));

__device__ __forceinline__ F2 f2splat(float s){ F2 r; r.x = s; r.y = s; return r; }
__device__ __forceinline__ F2 f2fma(F2 a, float b, F2 c){
    return __builtin_elementwise_fma(a, f2splat(b), c);
}
__device__ __forceinline__ float raw2alpha_f(float d){
    // 1 - exp(-softplus(d - 4) * 0.5) == 1 - (1 + e^(d-4))^(-1/2)
    return 1.0f - rsqrtf(1.0f + __expf(d - 4.0f));
}

// ---------------- kernel 0: transpose expert weights into a 48B/row table ----------------
// Wt[e*128 + i] = {We1[e][0..3][i]} {We1[e][4][i], We1[e][5][i], be1[e][i], Walpha[e][i]}
//                 {Wrgb[e][i][0..2], 0}
__global__ __launch_bounds__(128) void k_prep(
    const float* __restrict__ We1, const float* __restrict__ be1,
    const float* __restrict__ Wrgb, const float* __restrict__ Walpha,
    float* __restrict__ Wt)
{
    int e = blockIdx.x, t = threadIdx.x;     // 8 x 128
    const float* w = We1 + e*768;
    float* dst = Wt + (size_t)(e*128 + t)*12;
    dst[0]  = w[t];       dst[1]  = w[128+t];   dst[2]  = w[256+t]; dst[3] = w[384+t];
    dst[4]  = w[512+t];   dst[5]  = w[640+t];
    dst[6]  = be1[e*128+t];
    dst[7]  = Walpha[e*128+t];
    const float* wr = Wrgb + e*384 + 3*t;
    dst[8]  = wr[0];      dst[9]  = wr[1];      dst[10] = wr[2];    dst[11] = 0.f;
}

// ---------------- kernel 1: density alpha + gate + vd cache + ray_off ----------------
__global__ __launch_bounds__(256) void k_point(
    const float* __restrict__ pts, const float* __restrict__ vdirs,
    const int* __restrict__ ray_id,
    const float* __restrict__ Wd1, const float* __restrict__ bd1,
    const float* __restrict__ Wd2, const float* __restrict__ Wg,
    float* __restrict__ alpha0, float* __restrict__ g0a, int* __restrict__ eea,
    float4* __restrict__ vd, int* __restrict__ ray_off)
{
    __shared__ float4 WD4[128];   // {Wd1[0][i], Wd1[1][i], Wd1[2][i], bd1[i]}
    __shared__ float  WD2s[128];
    __shared__ float  WGs[8][6];
    int t = threadIdx.x;
    if (t < 128){
        WD4[t] = make_float4(Wd1[t], Wd1[128+t], Wd1[256+t], bd1[t]);
        WD2s[t] = Wd2[t];
    }
    if (t < 48) WGs[t & 7][t >> 3] = Wg[t];   // Wg[k][e] flat = k*8+e
    __syncthreads();

    int base = blockIdx.x * 2048 + t;         // 8 points/thread as 4 F2 pairs
    F2 px[4], py[4], pz[4], vx[4], vy[4], vz[4], dens[4];
    int rid0[4], rid1[4];
    #pragma unroll
    for (int q=0;q<4;q++){
        int p0 = base + (2*q)*256, p1 = p0 + 256;
        px[q] = (F2){pts[3*p0],   pts[3*p1]};
        py[q] = (F2){pts[3*p0+1], pts[3*p1+1]};
        pz[q] = (F2){pts[3*p0+2], pts[3*p1+2]};
        int r0 = ray_id[p0], r1 = ray_id[p1];
        rid0[q] = r0; rid1[q] = r1;
        vx[q] = (F2){vdirs[3*r0],   vdirs[3*r1]};
        vy[q] = (F2){vdirs[3*r0+1], vdirs[3*r1+1]};
        vz[q] = (F2){vdirs[3*r0+2], vdirs[3*r1+2]};
        dens[q] = f2splat(0.f);
    }
    // vd cache (one coalesced float4 per point) + ray segment boundaries
    #pragma unroll
    for (int q=0;q<4;q++){
        int p0 = base + (2*q)*256, p1 = p0 + 256;
        vd[p0] = make_float4(vx[q].x, vy[q].x, vz[q].x, 0.f);
        vd[p1] = make_float4(vx[q].y, vy[q].y, vz[q].y, 0.f);
        int prev0 = (p0 == 0) ? -1 : ray_id[p0-1];
        if (prev0 != rid0[q]) for (int r=prev0+1; r<=rid0[q]; ++r) ray_off[r] = p0;
        int prev1 = ray_id[p1-1];
        if (prev1 != rid1[q]) for (int r=prev1+1; r<=rid1[q]; ++r) ray_off[r] = p1;
        if (p1 == PTOT-1) for (int r=rid1[q]+1; r<=NRAYS; ++r) ray_off[r] = PTOT;
    }
    #pragma unroll 2
    for (int i=0;i<128;i++){
        float4 w = WD4[i]; float w2 = WD2s[i];
        #pragma unroll
        for (int q=0;q<4;q++){
            F2 h = f2fma(px[q], w.x, f2fma(py[q], w.y, f2fma(pz[q], w.z, f2splat(w.w))));
            h = __builtin_elementwise_max(h, f2splat(0.f));
            dens[q] = f2fma(h, w2, dens[q]);
        }
    }
    #pragma unroll
    for (int q=0;q<4;q++){
        float a0 = raw2alpha_f(dens[q].x);
        float a1 = raw2alpha_f(dens[q].y);
        alpha0[base + (2*q)*256]   = (a0 > THRESH) ? a0 : 0.f;
        alpha0[base + (2*q+1)*256] = (a1 > THRESH) ? a1 : 0.f;
    }
    // gate: top-2 of softmax over 8 experts, renormalized
    float m0[8], m1[8]; int i0[8], i1[8];
    #pragma unroll
    for (int j=0;j<8;j++){ m0[j]=-3.0e38f; m1[j]=-3.0e38f; i0[j]=0; i1[j]=0; }
    for (int e=0;e<8;e++){
        float w0=WGs[e][0],w1=WGs[e][1],w2=WGs[e][2],w3=WGs[e][3],w4=WGs[e][4],w5=WGs[e][5];
        #pragma unroll
        for (int q=0;q<4;q++){
            F2 l = f2fma(px[q],w0, f2fma(py[q],w1, f2fma(pz[q],w2,
                   f2fma(vx[q],w3, f2fma(vy[q],w4,
                   __builtin_elementwise_fma(vz[q], f2splat(w5), f2splat(0.f)))))));
            int j0 = 2*q, j1 = 2*q+1;
            float lx = l.x, ly = l.y;
            if (lx > m0[j0]){ m1[j0]=m0[j0]; i1[j0]=i0[j0]; m0[j0]=lx; i0[j0]=e; }
            else if (lx > m1[j0]){ m1[j0]=lx; i1[j0]=e; }
            if (ly > m0[j1]){ m1[j1]=m0[j1]; i1[j1]=i0[j1]; m0[j1]=ly; i0[j1]=e; }
            else if (ly > m1[j1]){ m1[j1]=ly; i1[j1]=e; }
        }
    }
    #pragma unroll
    for (int j=0;j<8;j++){
        float g0 = __fdividef(1.0f, 1.0f + __expf(m1[j]-m0[j]));
        g0a[base + j*256] = g0;
        eea[base + j*256] = i0[j] | (i1[j] << 8);
    }
}

// ---------------- kernel 2: transmittance scan -> keep mask + expert counts ----------------
__global__ __launch_bounds__(256) void k_scan0(const float* __restrict__ alpha0,
                                               const int* __restrict__ eea,
                                               const int* __restrict__ ray_off,
                                               unsigned char* __restrict__ keep,
                                               int* __restrict__ cntA)
{
    __shared__ int wcs[4][8];
    int t = threadIdx.x, lane = t & 63, w = t >> 6;
    int wid = blockIdx.x*4 + w;                      // wave = ray
    int c[8];
    #pragma unroll
    for (int e=0;e<8;e++) c[e]=0;
    int s = ray_off[wid], e = ray_off[wid+1];
    float carry = 1.f;
    for (int ch = s; ch < e; ch += 64){
        int p = ch + lane;
        bool in = p < e;
        float a = in ? alpha0[p] : 0.f;
        int  ee = in ? eea[p] : 0;
        float incl = 1.f - a;
        #pragma unroll
        for (int d=1; d<64; d<<=1){ float tt = __shfl_up(incl, d); if (lane >= d) incl *= tt; }
        float excl = __shfl_up(incl, 1); if (lane == 0) excl = 1.f;
        float w0 = a * carry * excl;
        int k = (in && w0 > THRESH) ? 1 : 0;
        if (in) keep[p] = (unsigned char)k;
        int e0 = ee & 255, e1 = (ee >> 8) & 255;
        #pragma unroll
        for (int x=0;x<8;x++){
            unsigned long long m0 = __ballot(k && e0==x);
            unsigned long long m1 = __ballot(k && e1==x);
            c[x] += __popcll(m0) + __popcll(m1);
        }
        carry *= __shfl(incl, 63);
    }
    if (lane == 0){
        #pragma unroll
        for (int x=0;x<8;x++) wcs[w][x] = c[x];
    }
    __syncthreads();
    if (t < 8){
        int sum = wcs[0][t]+wcs[1][t]+wcs[2][t]+wcs[3][t];
        if (sum) atomicAdd(&cntA[t], sum);
    }
}

// ---------------- kernel 3: fill entries (ballot-ranked; local prefix of cntA) ----------------
// entry.x = pid | (slot << 30), entry.y = gate weight bits
__global__ __launch_bounds__(256) void k_fill(const unsigned char* __restrict__ keep,
                                              const float* __restrict__ g0a,
                                              const int* __restrict__ eea,
                                              const int* __restrict__ cntA,
                                              int* __restrict__ curA,
                                              int2* __restrict__ ent)
{
    __shared__ int wc[4][8];
    __shared__ int wb[4][8];
    __shared__ int sOff[8];
    int t = threadIdx.x, lane = t & 63, w = t >> 6;
    unsigned long long lt = (1ull << lane) - 1ull;
    int base = blockIdx.x * 2048;

    int c[8];
    #pragma unroll
    for (int e=0;e<8;e++) c[e]=0;
    for (int j=0;j<8;j++){
        int p = base + (j*4 + w)*64 + lane;
        int k = keep[p];
        int ee = eea[p];
        int e0 = ee & 255, e1 = (ee >> 8) & 255;
        #pragma unroll
        for (int e=0;e<8;e++){
            unsigned long long m0 = __ballot(k && e0==e);
            unsigned long long m1 = __ballot(k && e1==e);
            c[e] += __popcll(m0) + __popcll(m1);
        }
    }
    if (lane == 0){
        #pragma unroll
        for (int e=0;e<8;e++) wc[w][e] = c[e];
    }
    if (t == 0){                                // local exclusive prefix of cntA
        int acc = 0;
        for (int e=0;e<8;e++){ sOff[e] = acc; acc += cntA[e]; }
    }
    __syncthreads();
    if (t < 8){
        int tot = wc[0][t]+wc[1][t]+wc[2][t]+wc[3][t];
        int b = sOff[t] + (tot ? atomicAdd(&curA[t], tot) : 0);
        wb[0][t] = b; b += wc[0][t];
        wb[1][t] = b; b += wc[1][t];
        wb[2][t] = b; b += wc[2][t];
        wb[3][t] = b;
    }
    __syncthreads();

    int cur[8];
    #pragma unroll
    for (int e=0;e<8;e++) cur[e] = wb[w][e];
    for (int j=0;j<8;j++){
        int p = base + (j*4 + w)*64 + lane;
        int k = keep[p];
        float g0 = g0a[p];
        int ee = eea[p];
        int e0 = ee & 255, e1 = (ee >> 8) & 255;
        #pragma unroll
        for (int e=0;e<8;e++){
            unsigned long long m0 = __ballot(k && e0==e);
            unsigned long long m1 = __ballot(k && e1==e);
            if (k && e0==e)
                ent[cur[e] + __popcll(m0 & lt)] = make_int2(p, __float_as_int(g0));
            if (k && e1==e)
                ent[cur[e] + __popcll(m0) + __popcll(m1 & lt)] =
                    make_int2(p | (1 << 30), __float_as_int(1.0f - g0));
            cur[e] += __popcll(m0) + __popcll(m1);
        }
    }
}

// ---------------- kernel 4: expert MLPs (scalar-F2 core, SMEM weights) ----------------
// 256 blocks/expert, 256 threads, 1024 entries/block (2 F2 pairs/thread), grid-stride safety.
// Weights read through uniform (scalar) loads from the transposed Wt table — no LDS, no
// barriers; dead blocks exit immediately. Records kept in VGPRs for the epilogue.
// NOTE (R7, prior session): MFMA variant measured SLOWER (99 vs 91 us) — scalar it is.
__global__ __launch_bounds__(256) void k_expert(
    const int2* __restrict__ ent, const int* __restrict__ cntA,
    const float* __restrict__ pts, const float4* __restrict__ vd,
    const float4* __restrict__ Wt4,
    float4* __restrict__ res)
{
    int e  = blockIdx.x >> 8;
    int bi = blockIdx.x & 255;
    // uniform (scalar) segment bounds — branchless, no LDS
    int s0 = 0, n = 0;
    #pragma unroll
    for (int i=0;i<8;i++){
        int c = cntA[i];
        s0 += (i < e) ? c : 0;
        n   = (i == e) ? c : n;
    }
    if (bi*1024 >= n) return;                    // uniform early exit, nothing staged
    const int2* eb = ent + s0;
    const float4* W = Wt4 + (size_t)e * 384;     // 128 rows x 3 float4
    int t = threadIdx.x;

    for (int base = bi*1024; base < n; base += 256*1024){
        F2 x0[2],x1[2],x2[2],x3[2],x4[2],x5[2];
        F2 ar[2],ag[2],ab[2],aa[2];
        int2 rr[4];
        #pragma unroll
        for (int pr=0;pr<2;pr++){
            int idx0 = base + t + pr*512, idx1 = idx0 + 256;
            int2 r0 = (idx0 < n) ? eb[idx0] : make_int2(0,0);
            int2 r1 = (idx1 < n) ? eb[idx1] : make_int2(0,0);
            rr[2*pr] = r0; rr[2*pr+1] = r1;
            int p0 = r0.x & 0x0FFFFFFF, p1 = r1.x & 0x0FFFFFFF;
            x0[pr] = (F2){pts[3*p0],   pts[3*p1]};
            x1[pr] = (F2){pts[3*p0+1], pts[3*p1+1]};
            x2[pr] = (F2){pts[3*p0+2], pts[3*p1+2]};
            float4 v0 = vd[p0], v1 = vd[p1];
            x3[pr] = (F2){v0.x, v1.x};
            x4[pr] = (F2){v0.y, v1.y};
            x5[pr] = (F2){v0.z, v1.z};
            ar[pr] = f2splat(0.f); ag[pr] = f2splat(0.f);
            ab[pr] = f2splat(0.f); aa[pr] = f2splat(0.f);
        }
        #pragma unroll 2
        for (int i=0;i<128;i++){
            float4 wa = W[3*i], wb = W[3*i+1], wc = W[3*i+2];
            #pragma unroll
            for (int pr=0;pr<2;pr++){
                F2 h = f2fma(x0[pr],wa.x, f2fma(x1[pr],wa.y, f2fma(x2[pr],wa.z,
                       f2fma(x3[pr],wa.w, f2fma(x4[pr],wb.x, f2fma(x5[pr],wb.y,
                       f2splat(wb.z)))))));
                h = __builtin_elementwise_max(h, f2splat(0.f));
                ar[pr] = f2fma(h, wc.x, ar[pr]);
                ag[pr] = f2fma(h, wc.y, ag[pr]);
                ab[pr] = f2fma(h, wc.z, ab[pr]);
                aa[pr] = f2fma(h, wb.w, aa[pr]);
            }
        }
        #pragma unroll
        for (int pr=0;pr<2;pr++){
            #pragma unroll
            for (int sel=0; sel<2; sel++){
                int idx = base + t + pr*512 + sel*256;
                if (idx < n){
                    int2 rec = rr[2*pr+sel];
                    float vr = sel ? ar[pr].y : ar[pr].x;
                    float vg = sel ? ag[pr].y : ag[pr].x;
                    float vb = sel ? ab[pr].y : ab[pr].x;
                    float va = sel ? aa[pr].y : aa[pr].x;
                    float sr = __fdividef(1.0f, 1.0f + __expf(-vr));
                    float sg = __fdividef(1.0f, 1.0f + __expf(-vg));
                    float sb = __fdividef(1.0f, 1.0f + __expf(-vb));
                    float a  = raw2alpha_f(va);
                    float g  = __int_as_float(rec.y);
                    int pp   = rec.x & 0x0FFFFFFF;
                    int slot = ((unsigned)rec.x) >> 30;
                    res[2*(size_t)pp + slot] = make_float4(g*sr, g*sg, g*sb, g*a);
                }
            }
        }
    }
}

// ---------------- kernel 5: final per-ray composite ----------------
__global__ __launch_bounds__(256) void k_scan1(const float4* __restrict__ res,
                                               const unsigned char* __restrict__ keep,
                                               const int* __restrict__ ray_off,
                                               const float* __restrict__ bg,
                                               float* __restrict__ out)
{
    int wid  = (blockIdx.x*blockDim.x + threadIdx.x) >> 6;   // wave = ray
    int lane = threadIdx.x & 63;
    if (wid >= NRAYS) return;
    int s = ray_off[wid], e = ray_off[wid+1];
    float carry = 1.f;
    float accx = 0.f, accy = 0.f, accz = 0.f;
    for (int c = s; c < e; c += 64){
        int p = c + lane;
        float4 v = make_float4(0.f,0.f,0.f,0.f);
        if (p < e && keep[p]){
            float4 v0 = res[2*(size_t)p];
            float4 v1 = res[2*(size_t)p + 1];
            v = make_float4(v0.x+v1.x, v0.y+v1.y, v0.z+v1.z, v0.w+v1.w);
        }
        float a = v.w;
        float incl = 1.f - a;
        #pragma unroll
        for (int d=1; d<64; d<<=1){ float tt = __shfl_up(incl, d); if (lane >= d) incl *= tt; }
        float excl = __shfl_up(incl, 1); if (lane == 0) excl = 1.f;
        float w = a * carry * excl;
        accx = fmaf(w, v.x, accx);
        accy = fmaf(w, v.y, accy);
        accz = fmaf(w, v.z, accz);
        carry *= __shfl(incl, 63);
    }
    #pragma unroll
    for (int d=32; d; d>>=1){
        accx += __shfl_xor(accx, d);
        accy += __shfl_xor(accy, d);
        accz += __shfl_xor(accz, d);
    }
    if (lane == 0){
        out[3*wid+0] = accx + carry*bg[0];
        out[3*wid+1] = accy + carry*bg[1];
        out[3*wid+2] = accz + carry*bg[2];
    }
}

extern "C" void kernel_launch(void* const* d_in, const int* in_sizes, int n_in,
                              void* d_out, int out_size, void* d_ws, size_t ws_size,
                              hipStream_t stream)
{
    const float* pts    = (const float*)d_in[0];
    const float* vdirs  = (const float*)d_in[1];
    const float* bg     = (const float*)d_in[2];
    const float* Wd1    = (const float*)d_in[3];
    const float* bd1    = (const float*)d_in[4];
    const float* Wd2    = (const float*)d_in[5];
    const float* Wg     = (const float*)d_in[6];
    const float* We1    = (const float*)d_in[7];
    const float* be1    = (const float*)d_in[8];
    const float* Wrgb   = (const float*)d_in[9];
    const float* Walpha = (const float*)d_in[10];
    const int*   ray_id = (const int*)d_in[11];
    float* out = (float*)d_out;

    char* ws = (char*)d_ws;
    size_t off = 0;
    float* alpha0        = (float*)(ws + off); off += (size_t)PTOT*4;       // 4MB
    float* g0a           = (float*)(ws + off); off += (size_t)PTOT*4;       // 4MB
    int*   eea           = (int*)  (ws + off); off += (size_t)PTOT*4;       // 4MB
    unsigned char* keep  = (unsigned char*)(ws + off); off += (size_t)PTOT; // 1MB
    int*   ray_off       = (int*)  (ws + off); off += 33024;                // 8193+ ints
    int*   cntA          = (int*)  (ws + off); off += 256;
    int*   curA          = (int*)  (ws + off); off += 256;
    off = (off + 255) & ~(size_t)255;
    float4* vd           = (float4*)(ws + off); off += (size_t)PTOT*16;     // 16MB
    int2*  ent           = (int2*) (ws + off); off += (size_t)2*PTOT*8;     // 16MB
    float4* res          = (float4*)(ws + off); off += ((size_t)2*PTOT+2)*16; // 32MB
    off = (off + 255) & ~(size_t)255;
    float* Wt            = (float*)(ws + off); off += 8*128*12*4;           // 48KB transposed weights

    hipMemsetAsync(cntA, 0, 512, stream);   // cntA + curA (adjacent)

    k_prep  <<<8, 128, 0, stream>>>(We1, be1, Wrgb, Walpha, Wt);
    k_point <<<PTOT/2048, 256, 0, stream>>>(pts, vdirs, ray_id, Wd1, bd1, Wd2, Wg,
                                            alpha0, g0a, eea, vd, ray_off);
    k_scan0 <<<NRAYS/4, 256, 0, stream>>>(alpha0, eea, ray_off, keep, cntA);
    k_fill  <<<PTOT/2048, 256, 0, stream>>>(keep, g0a, eea, cntA, curA, ent);
    k_expert<<<8*256, 256, 0, stream>>>(ent, cntA, pts, vd, (const float4*)Wt, res);
    k_scan1 <<<NRAYS*64/256, 256, 0, stream>>>(res, keep, ray_off, bg, out);
}

// Round 2
// 259.068 us; speedup vs baseline: 1.1040x; 1.1040x over previous
//
#include <hip/hip_runtime.h>

#define PTOT   1048576
#define NRAYS  8192
#define THRESH 1e-4f

typedef float F2 __attribute__((ext_vector_type(2)));

__device__ __forceinline__ F2 f2splat(float s){ F2 r; r.x = s; r.y = s; return r; }
__device__ __forceinline__ F2 f2fma(F2 a, float b, F2 c){
    return __builtin_elementwise_fma(a, f2splat(b), c);
}
__device__ __forceinline__ float raw2alpha_f(float d){
    // 1 - exp(-softplus(d - 4) * 0.5) == 1 - (1 + e^(d-4))^(-1/2)
    return 1.0f - rsqrtf(1.0f + __expf(d - 4.0f));
}

// ---------------- kernel 1: density alpha + gate + ray_off ----------------
__global__ __launch_bounds__(256) void k_point(
    const float* __restrict__ pts, const float* __restrict__ vdirs,
    const int* __restrict__ ray_id,
    const float* __restrict__ Wd1, const float* __restrict__ bd1,
    const float* __restrict__ Wd2, const float* __restrict__ Wg,
    float* __restrict__ alpha0, float* __restrict__ g0a, int* __restrict__ eea,
    int* __restrict__ ray_off)
{
    __shared__ float4 WD4[128];   // {Wd1[0][i], Wd1[1][i], Wd1[2][i], bd1[i]}
    __shared__ float  WD2s[128];
    __shared__ float  WGs[8][6];
    int t = threadIdx.x;
    if (t < 128){
        WD4[t] = make_float4(Wd1[t], Wd1[128+t], Wd1[256+t], bd1[t]);
        WD2s[t] = Wd2[t];
    }
    if (t < 48) WGs[t & 7][t >> 3] = Wg[t];   // Wg[k][e] flat = k*8+e
    __syncthreads();

    int base = blockIdx.x * 2048 + t;         // 8 points/thread as 4 F2 pairs
    F2 px[4], py[4], pz[4], vx[4], vy[4], vz[4], dens[4];
    int rid0[4], rid1[4];
    #pragma unroll
    for (int q=0;q<4;q++){
        int p0 = base + (2*q)*256, p1 = p0 + 256;
        px[q] = (F2){pts[3*p0],   pts[3*p1]};
        py[q] = (F2){pts[3*p0+1], pts[3*p1+1]};
        pz[q] = (F2){pts[3*p0+2], pts[3*p1+2]};
        int r0 = ray_id[p0], r1 = ray_id[p1];
        rid0[q] = r0; rid1[q] = r1;
        vx[q] = (F2){vdirs[3*r0],   vdirs[3*r1]};
        vy[q] = (F2){vdirs[3*r0+1], vdirs[3*r1+1]};
        vz[q] = (F2){vdirs[3*r0+2], vdirs[3*r1+2]};
        dens[q] = f2splat(0.f);
    }
    // ray segment boundaries
    #pragma unroll
    for (int q=0;q<4;q++){
        int p0 = base + (2*q)*256, p1 = p0 + 256;
        int prev0 = (p0 == 0) ? -1 : ray_id[p0-1];
        if (prev0 != rid0[q]) for (int r=prev0+1; r<=rid0[q]; ++r) ray_off[r] = p0;
        int prev1 = ray_id[p1-1];
        if (prev1 != rid1[q]) for (int r=prev1+1; r<=rid1[q]; ++r) ray_off[r] = p1;
        if (p1 == PTOT-1) for (int r=rid1[q]+1; r<=NRAYS; ++r) ray_off[r] = PTOT;
    }
    #pragma unroll 2
    for (int i=0;i<128;i++){
        float4 w = WD4[i]; float w2 = WD2s[i];
        #pragma unroll
        for (int q=0;q<4;q++){
            F2 h = f2fma(px[q], w.x, f2fma(py[q], w.y, f2fma(pz[q], w.z, f2splat(w.w))));
            h = __builtin_elementwise_max(h, f2splat(0.f));
            dens[q] = f2fma(h, w2, dens[q]);
        }
    }
    #pragma unroll
    for (int q=0;q<4;q++){
        float a0 = raw2alpha_f(dens[q].x);
        float a1 = raw2alpha_f(dens[q].y);
        alpha0[base + (2*q)*256]   = (a0 > THRESH) ? a0 : 0.f;
        alpha0[base + (2*q+1)*256] = (a1 > THRESH) ? a1 : 0.f;
    }
    // gate: top-2 of softmax over 8 experts, renormalized
    float m0[8], m1[8]; int i0[8], i1[8];
    #pragma unroll
    for (int j=0;j<8;j++){ m0[j]=-3.0e38f; m1[j]=-3.0e38f; i0[j]=0; i1[j]=0; }
    for (int e=0;e<8;e++){
        float w0=WGs[e][0],w1=WGs[e][1],w2=WGs[e][2],w3=WGs[e][3],w4=WGs[e][4],w5=WGs[e][5];
        #pragma unroll
        for (int q=0;q<4;q++){
            F2 l = f2fma(px[q],w0, f2fma(py[q],w1, f2fma(pz[q],w2,
                   f2fma(vx[q],w3, f2fma(vy[q],w4,
                   __builtin_elementwise_fma(vz[q], f2splat(w5), f2splat(0.f)))))));
            int j0 = 2*q, j1 = 2*q+1;
            float lx = l.x, ly = l.y;
            if (lx > m0[j0]){ m1[j0]=m0[j0]; i1[j0]=i0[j0]; m0[j0]=lx; i0[j0]=e; }
            else if (lx > m1[j0]){ m1[j0]=lx; i1[j0]=e; }
            if (ly > m0[j1]){ m1[j1]=m0[j1]; i1[j1]=i0[j1]; m0[j1]=ly; i0[j1]=e; }
            else if (ly > m1[j1]){ m1[j1]=ly; i1[j1]=e; }
        }
    }
    #pragma unroll
    for (int j=0;j<8;j++){
        float g0 = __fdividef(1.0f, 1.0f + __expf(m1[j]-m0[j]));
        g0a[base + j*256] = g0;
        eea[base + j*256] = i0[j] | (i1[j] << 8);
    }
}

// ---------------- kernel 2: transmittance scan -> keep mask + expert counts ----------------
__global__ __launch_bounds__(256) void k_scan0(const float* __restrict__ alpha0,
                                               const int* __restrict__ eea,
                                               const int* __restrict__ ray_off,
                                               unsigned char* __restrict__ keep,
                                               int* __restrict__ cntA)
{
    __shared__ int wcs[4][8];
    int t = threadIdx.x, lane = t & 63, w = t >> 6;
    int wid = blockIdx.x*4 + w;                      // wave = ray
    int c[8];
    #pragma unroll
    for (int e=0;e<8;e++) c[e]=0;
    int s = ray_off[wid], e = ray_off[wid+1];
    float carry = 1.f;
    for (int ch = s; ch < e; ch += 64){
        int p = ch + lane;
        bool in = p < e;
        float a = in ? alpha0[p] : 0.f;
        int  ee = in ? eea[p] : 0;
        float incl = 1.f - a;
        #pragma unroll
        for (int d=1; d<64; d<<=1){ float tt = __shfl_up(incl, d); if (lane >= d) incl *= tt; }
        float excl = __shfl_up(incl, 1); if (lane == 0) excl = 1.f;
        float w0 = a * carry * excl;
        int k = (in && w0 > THRESH) ? 1 : 0;
        if (in) keep[p] = (unsigned char)k;
        int e0 = ee & 255, e1 = (ee >> 8) & 255;
        #pragma unroll
        for (int x=0;x<8;x++){
            unsigned long long m0 = __ballot(k && e0==x);
            unsigned long long m1 = __ballot(k && e1==x);
            c[x] += __popcll(m0) + __popcll(m1);
        }
        carry *= __shfl(incl, 63);
    }
    if (lane == 0){
        #pragma unroll
        for (int x=0;x<8;x++) wcs[w][x] = c[x];
    }
    __syncthreads();
    if (t < 8){
        int sum = wcs[0][t]+wcs[1][t]+wcs[2][t]+wcs[3][t];
        if (sum) atomicAdd(&cntA[t], sum);
    }
}

// ---------------- kernel 3: fill packed 32B entries (ballot-ranked) ----------------
// ent4[2*k]   = {x, y, z, vx}
// ent4[2*k+1] = {vy, vz, gate, asfloat(pid | slot<<30)}
__global__ __launch_bounds__(256) void k_fill(const unsigned char* __restrict__ keep,
                                              const float* __restrict__ g0a,
                                              const int* __restrict__ eea,
                                              const int* __restrict__ cntA,
                                              int* __restrict__ curA,
                                              const float* __restrict__ pts,
                                              const int* __restrict__ ray_id,
                                              const float* __restrict__ vdirs,
                                              float4* __restrict__ ent4)
{
    __shared__ int wc[4][8];
    __shared__ int wb[4][8];
    __shared__ int sOff[8];
    int t = threadIdx.x, lane = t & 63, w = t >> 6;
    unsigned long long lt = (1ull << lane) - 1ull;
    int base = blockIdx.x * 2048;

    int c[8];
    #pragma unroll
    for (int e=0;e<8;e++) c[e]=0;
    for (int j=0;j<8;j++){
        int p = base + (j*4 + w)*64 + lane;
        int k = keep[p];
        int ee = eea[p];
        int e0 = ee & 255, e1 = (ee >> 8) & 255;
        #pragma unroll
        for (int e=0;e<8;e++){
            unsigned long long m0 = __ballot(k && e0==e);
            unsigned long long m1 = __ballot(k && e1==e);
            c[e] += __popcll(m0) + __popcll(m1);
        }
    }
    if (lane == 0){
        #pragma unroll
        for (int e=0;e<8;e++) wc[w][e] = c[e];
    }
    if (t == 0){                                // local exclusive prefix of cntA
        int acc = 0;
        for (int e=0;e<8;e++){ sOff[e] = acc; acc += cntA[e]; }
    }
    __syncthreads();
    if (t < 8){
        int tot = wc[0][t]+wc[1][t]+wc[2][t]+wc[3][t];
        int b = sOff[t] + (tot ? atomicAdd(&curA[t], tot) : 0);
        wb[0][t] = b; b += wc[0][t];
        wb[1][t] = b; b += wc[1][t];
        wb[2][t] = b; b += wc[2][t];
        wb[3][t] = b;
    }
    __syncthreads();

    int cur[8];
    #pragma unroll
    for (int e=0;e<8;e++) cur[e] = wb[w][e];
    for (int j=0;j<8;j++){
        int p = base + (j*4 + w)*64 + lane;
        int k = keep[p];
        float g0 = g0a[p];
        int ee = eea[p];
        // coalesced point data; near-uniform viewdir gather (L1 broadcast)
        float x = pts[3*p], y = pts[3*p+1], z = pts[3*p+2];
        int r = ray_id[p];
        float vx = vdirs[3*r], vy = vdirs[3*r+1], vz = vdirs[3*r+2];
        int e0 = ee & 255, e1 = (ee >> 8) & 255;
        #pragma unroll
        for (int e=0;e<8;e++){
            unsigned long long m0 = __ballot(k && e0==e);
            unsigned long long m1 = __ballot(k && e1==e);
            if (k && e0==e){
                int kk = cur[e] + __popcll(m0 & lt);
                ent4[2*(size_t)kk]   = make_float4(x, y, z, vx);
                ent4[2*(size_t)kk+1] = make_float4(vy, vz, g0, __int_as_float(p));
            }
            if (k && e1==e){
                int kk = cur[e] + __popcll(m0) + __popcll(m1 & lt);
                ent4[2*(size_t)kk]   = make_float4(x, y, z, vx);
                ent4[2*(size_t)kk+1] = make_float4(vy, vz, 1.0f - g0,
                                                   __int_as_float(p | (1 << 30)));
            }
            cur[e] += __popcll(m0) + __popcll(m1);
        }
    }
}

// ---------------- kernel 4: expert MLPs (scalar-F2 core, LDS weights, packed entries) ----
// 512 blocks/expert, 256 threads, 8 entries/thread as 4 F2 pairs (proven R0 structure).
// All global reads are coalesced 16B streams now; g/pid arrive with the entry.
// NOTE: MFMA variant (prior session R7) measured SLOWER (99 vs 91 us) — scalar it is.
// NOTE: R1 scalar-weight variant (s_load Wt, 2 pairs) measured 127 us — LDS + 4 pairs it is.
__global__ __launch_bounds__(256) void k_expert(
    const float4* __restrict__ ent4, const int* __restrict__ cntA,
    const float* __restrict__ We1, const float* __restrict__ be1,
    const float* __restrict__ Wrgb, const float* __restrict__ Walpha,
    float4* __restrict__ res)
{
    int e    = blockIdx.x >> 9;
    int bi   = blockIdx.x & 511;
    int base = bi * 2048;

    __shared__ float4 WA[128];   // We1[e][0..3][i]
    __shared__ float4 WB[128];   // We1[e][4][i], We1[e][5][i], be1[e][i], Walpha[e][i]
    __shared__ float4 WC[128];   // Wrgb[e][i][0..2], 0
    __shared__ int sSeg[2];      // {segment start, n}
    int t = threadIdx.x;
    if (t < 128){
        const float* w = We1 + e*768;
        WA[t] = make_float4(w[t], w[128+t], w[256+t], w[384+t]);
        WB[t] = make_float4(w[512+t], w[640+t], be1[e*128+t], Walpha[e*128+t]);
        const float* wr = Wrgb + e*384 + 3*t;
        WC[t] = make_float4(wr[0], wr[1], wr[2], 0.f);
    }
    if (t == 0){
        int acc = 0;
        for (int i=0;i<e;i++) acc += cntA[i];
        sSeg[0] = acc; sSeg[1] = cntA[e];
    }
    __syncthreads();
    int n = sSeg[1];
    if (base >= n) return;                      // uniform exit (post-barrier)
    const float4* eb = ent4 + 2*(size_t)sSeg[0];

    F2 x0[4],x1[4],x2[4],x3[4],x4[4],x5[4];
    F2 ar[4],ag[4],ab[4],aa[4];
    float gg[8]; int bb[8];
    #pragma unroll
    for (int pr=0;pr<4;pr++){
        int idx0 = base + t + (2*pr)*256, idx1 = idx0 + 256;
        float4 a0 = make_float4(0,0,0,0), b0 = a0, a1 = a0, b1 = a0;
        if (idx0 < n){ a0 = eb[2*idx0]; b0 = eb[2*idx0+1]; }
        if (idx1 < n){ a1 = eb[2*idx1]; b1 = eb[2*idx1+1]; }
        x0[pr] = (F2){a0.x, a1.x};
        x1[pr] = (F2){a0.y, a1.y};
        x2[pr] = (F2){a0.z, a1.z};
        x3[pr] = (F2){a0.w, a1.w};
        x4[pr] = (F2){b0.x, b1.x};
        x5[pr] = (F2){b0.y, b1.y};
        gg[2*pr] = b0.z;  gg[2*pr+1] = b1.z;
        bb[2*pr] = __float_as_int(b0.w); bb[2*pr+1] = __float_as_int(b1.w);
        ar[pr] = f2splat(0.f); ag[pr] = f2splat(0.f);
        ab[pr] = f2splat(0.f); aa[pr] = f2splat(0.f);
    }
    #pragma unroll 2
    for (int i=0;i<128;i++){
        float4 wa = WA[i], wb = WB[i], wc = WC[i];
        #pragma unroll
        for (int pr=0;pr<4;pr++){
            F2 h = f2fma(x0[pr],wa.x, f2fma(x1[pr],wa.y, f2fma(x2[pr],wa.z,
                   f2fma(x3[pr],wa.w, f2fma(x4[pr],wb.x, f2fma(x5[pr],wb.y,
                   f2splat(wb.z)))))));
            h = __builtin_elementwise_max(h, f2splat(0.f));
            ar[pr] = f2fma(h, wc.x, ar[pr]);
            ag[pr] = f2fma(h, wc.y, ag[pr]);
            ab[pr] = f2fma(h, wc.z, ab[pr]);
            aa[pr] = f2fma(h, wb.w, aa[pr]);
        }
    }
    #pragma unroll
    for (int pr=0;pr<4;pr++){
        #pragma unroll
        for (int sel=0; sel<2; sel++){
            int idx = base + t + (2*pr+sel)*256;
            if (idx < n){
                float vr = sel ? ar[pr].y : ar[pr].x;
                float vg = sel ? ag[pr].y : ag[pr].x;
                float vb = sel ? ab[pr].y : ab[pr].x;
                float va = sel ? aa[pr].y : aa[pr].x;
                float sr = __fdividef(1.0f, 1.0f + __expf(-vr));
                float sg = __fdividef(1.0f, 1.0f + __expf(-vg));
                float sb = __fdividef(1.0f, 1.0f + __expf(-vb));
                float a  = raw2alpha_f(va);
                float g  = gg[2*pr+sel];
                int bits = bb[2*pr+sel];
                int pp   = bits & 0x0FFFFFFF;
                int slot = ((unsigned)bits) >> 30;
                res[2*(size_t)pp + slot] = make_float4(g*sr, g*sg, g*sb, g*a);
            }
        }
    }
}

// ---------------- kernel 5: final per-ray composite ----------------
__global__ __launch_bounds__(256) void k_scan1(const float4* __restrict__ res,
                                               const unsigned char* __restrict__ keep,
                                               const int* __restrict__ ray_off,
                                               const float* __restrict__ bg,
                                               float* __restrict__ out)
{
    int wid  = (blockIdx.x*blockDim.x + threadIdx.x) >> 6;   // wave = ray
    int lane = threadIdx.x & 63;
    if (wid >= NRAYS) return;
    int s = ray_off[wid], e = ray_off[wid+1];
    float carry = 1.f;
    float accx = 0.f, accy = 0.f, accz = 0.f;
    for (int c = s; c < e; c += 64){
        int p = c + lane;
        float4 v = make_float4(0.f,0.f,0.f,0.f);
        if (p < e && keep[p]){
            float4 v0 = res[2*(size_t)p];
            float4 v1 = res[2*(size_t)p + 1];
            v = make_float4(v0.x+v1.x, v0.y+v1.y, v0.z+v1.z, v0.w+v1.w);
        }
        float a = v.w;
        float incl = 1.f - a;
        #pragma unroll
        for (int d=1; d<64; d<<=1){ float tt = __shfl_up(incl, d); if (lane >= d) incl *= tt; }
        float excl = __shfl_up(incl, 1); if (lane == 0) excl = 1.f;
        float w = a * carry * excl;
        accx = fmaf(w, v.x, accx);
        accy = fmaf(w, v.y, accy);
        accz = fmaf(w, v.z, accz);
        carry *= __shfl(incl, 63);
    }
    #pragma unroll
    for (int d=32; d; d>>=1){
        accx += __shfl_xor(accx, d);
        accy += __shfl_xor(accy, d);
        accz += __shfl_xor(accz, d);
    }
    if (lane == 0){
        out[3*wid+0] = accx + carry*bg[0];
        out[3*wid+1] = accy + carry*bg[1];
        out[3*wid+2] = accz + carry*bg[2];
    }
}

extern "C" void kernel_launch(void* const* d_in, const int* in_sizes, int n_in,
                              void* d_out, int out_size, void* d_ws, size_t ws_size,
                              hipStream_t stream)
{
    const float* pts    = (const float*)d_in[0];
    const float* vdirs  = (const float*)d_in[1];
    const float* bg     = (const float*)d_in[2];
    const float* Wd1    = (const float*)d_in[3];
    const float* bd1    = (const float*)d_in[4];
    const float* Wd2    = (const float*)d_in[5];
    const float* Wg     = (const float*)d_in[6];
    const float* We1    = (const float*)d_in[7];
    const float* be1    = (const float*)d_in[8];
    const float* Wrgb   = (const float*)d_in[9];
    const float* Walpha = (const float*)d_in[10];
    const int*   ray_id = (const int*)d_in[11];
    float* out = (float*)d_out;

    // Workspace layout (with liveness-based overlay):
    //   [keep 1MB][ray_off][cntA][curA]
    //   [A: alpha0 4MB | g0a 4MB | eea 4MB]   <- dead after k_fill
    //   res (32MB) OVERLAYS region A (written only in k_expert, after k_fill)
    //   [ent4 64MB]  placed past res's 32MB span (live during k_fill -> no overlap with A)
    // Total ~98MB.
    char* ws = (char*)d_ws;
    size_t off = 0;
    unsigned char* keep  = (unsigned char*)(ws + off); off += (size_t)PTOT;   // 1MB
    int*   ray_off       = (int*)  (ws + off); off += 33024;                  // 8193+ ints
    int*   cntA          = (int*)  (ws + off); off += 256;
    int*   curA          = (int*)  (ws + off); off += 256;
    off = (off + 255) & ~(size_t)255;
    size_t offA = off;
    float* alpha0        = (float*)(ws + offA);                                // 4MB
    float* g0a           = (float*)(ws + offA + (size_t)PTOT*4);               // 4MB
    int*   eea           = (int*)  (ws + offA + (size_t)PTOT*8);               // 4MB
    float4* res          = (float4*)(ws + offA);            // 32MB+32B, overlays the above
    size_t resBytes      = ((size_t)2*PTOT + 2) * 16;
    size_t offE          = (offA + resBytes + 255) & ~(size_t)255;
    float4* ent4         = (float4*)(ws + offE);            // 2*PTOT entries * 32B = 64MB

    hipMemsetAsync(cntA, 0, 512, stream);   // cntA + curA (adjacent)

    k_point <<<PTOT/2048, 256, 0, stream>>>(pts, vdirs, ray_id, Wd1, bd1, Wd2, Wg,
                                            alpha0, g0a, eea, ray_off);
    k_scan0 <<<NRAYS/4, 256, 0, stream>>>(alpha0, eea, ray_off, keep, cntA);
    k_fill  <<<PTOT/2048, 256, 0, stream>>>(keep, g0a, eea, cntA, curA,
                                            pts, ray_id, vdirs, ent4);
    k_expert<<<8*512, 256, 0, stream>>>(ent4, cntA, We1, be1, Wrgb, Walpha, res);
    k_scan1 <<<NRAYS*64/256, 256, 0, stream>>>(res, keep, ray_off, bg, out);
}

// Round 3
// 257.752 us; speedup vs baseline: 1.1096x; 1.0051x over previous
//
#include <hip/hip_runtime.h>

#define PTOT   1048576
#define NRAYS  8192
#define THRESH 1e-4f

typedef float F2 __attribute__((ext_vector_type(2)));
typedef union { float4 q; struct { F2 lo, hi; } h; } Q2;

__device__ __forceinline__ F2 f2splat(float s){ F2 r; r.x = s; r.y = s; return r; }
__device__ __forceinline__ F2 f2fma(F2 a, float b, F2 c){
    return __builtin_elementwise_fma(a, f2splat(b), c);
}
__device__ __forceinline__ float raw2alpha_f(float d){
    // 1 - exp(-softplus(d - 4) * 0.5) == 1 - (1 + e^(d-4))^(-1/2)
    return 1.0f - rsqrtf(1.0f + __expf(d - 4.0f));
}

// ---- packed-FP32 VOP3P helpers: one v_pk_fma_f32 = 2 fp32 FMAs --------------------
// op_sel[n]   : dword of src n feeding the LOW  result
// op_sel_hi[n]: dword of src n feeding the HIGH result
// broadcast dword0 -> sel=0,hi=0 ; broadcast dword1 -> sel=1,hi=1 ; vector -> sel=0,hi=1
// d = a * w.lo + c
__device__ __forceinline__ F2 pk_fma_lo(F2 a, F2 w, F2 c){
    F2 d;
    asm("v_pk_fma_f32 %0, %1, %2, %3 op_sel:[0,0,0] op_sel_hi:[1,0,1]"
        : "=v"(d) : "v"(a), "v"(w), "v"(c));
    return d;
}
// d = a * w.hi + c
__device__ __forceinline__ F2 pk_fma_hi(F2 a, F2 w, F2 c){
    F2 d;
    asm("v_pk_fma_f32 %0, %1, %2, %3 op_sel:[0,1,0] op_sel_hi:[1,1,1]"
        : "=v"(d) : "v"(a), "v"(w), "v"(c));
    return d;
}
// d = a * w.hi + splat(c.lo)
__device__ __forceinline__ F2 pk_fma_hi_clo(F2 a, F2 w, F2 c){
    F2 d;
    asm("v_pk_fma_f32 %0, %1, %2, %3 op_sel:[0,1,0] op_sel_hi:[1,1,0]"
        : "=v"(d) : "v"(a), "v"(w), "v"(c));
    return d;
}
// d = a * w.lo + splat(c.hi)
__device__ __forceinline__ F2 pk_fma_lo_chi(F2 a, F2 w, F2 c){
    F2 d;
    asm("v_pk_fma_f32 %0, %1, %2, %3 op_sel:[0,0,1] op_sel_hi:[1,0,1]"
        : "=v"(d) : "v"(a), "v"(w), "v"(c));
    return d;
}
__device__ __forceinline__ F2 f2relu(F2 a){
    return __builtin_elementwise_max(a, f2splat(0.f));   // 2x v_max_f32 (no pk_max_f32)
}

// ---------------- kernel 1: density alpha + gate + vd cache + ray_off ----------------
__global__ __launch_bounds__(256) void k_point(
    const float* __restrict__ pts, const float* __restrict__ vdirs,
    const int* __restrict__ ray_id,
    const float* __restrict__ Wd1, const float* __restrict__ bd1,
    const float* __restrict__ Wd2, const float* __restrict__ Wg,
    float* __restrict__ alpha0, float* __restrict__ g0a, int* __restrict__ eea,
    float4* __restrict__ vd, int* __restrict__ ray_off)
{
    __shared__ float4 WD4[128];   // {Wd1[0][i], Wd1[1][i], Wd1[2][i], bd1[i]}
    __shared__ F2     WD2v[128];  // {Wd2[i], Wd2[i]}
    __shared__ float  WGs[8][6];
    int t = threadIdx.x;
    if (t < 128){
        WD4[t] = make_float4(Wd1[t], Wd1[128+t], Wd1[256+t], bd1[t]);
        WD2v[t] = (F2){Wd2[t], Wd2[t]};
    }
    if (t < 48) WGs[t & 7][t >> 3] = Wg[t];   // Wg[k][e] flat = k*8+e
    __syncthreads();

    int base = blockIdx.x * 2048 + t;         // 8 points/thread as 4 F2 pairs
    F2 px[4], py[4], pz[4], vx[4], vy[4], vz[4], dens[4];
    int rid0[4], rid1[4];
    #pragma unroll
    for (int q=0;q<4;q++){
        int p0 = base + (2*q)*256, p1 = p0 + 256;
        px[q] = (F2){pts[3*p0],   pts[3*p1]};
        py[q] = (F2){pts[3*p0+1], pts[3*p1+1]};
        pz[q] = (F2){pts[3*p0+2], pts[3*p1+2]};
        int r0 = ray_id[p0], r1 = ray_id[p1];
        rid0[q] = r0; rid1[q] = r1;
        vx[q] = (F2){vdirs[3*r0],   vdirs[3*r1]};
        vy[q] = (F2){vdirs[3*r0+1], vdirs[3*r1+1]};
        vz[q] = (F2){vdirs[3*r0+2], vdirs[3*r1+2]};
        dens[q] = f2splat(0.f);
    }
    // vd cache (one coalesced float4 per point) + ray segment boundaries
    #pragma unroll
    for (int q=0;q<4;q++){
        int p0 = base + (2*q)*256, p1 = p0 + 256;
        vd[p0] = make_float4(vx[q].x, vy[q].x, vz[q].x, 0.f);
        vd[p1] = make_float4(vx[q].y, vy[q].y, vz[q].y, 0.f);
        int prev0 = (p0 == 0) ? -1 : ray_id[p0-1];
        if (prev0 != rid0[q]) for (int r=prev0+1; r<=rid0[q]; ++r) ray_off[r] = p0;
        int prev1 = ray_id[p1-1];
        if (prev1 != rid1[q]) for (int r=prev1+1; r<=rid1[q]; ++r) ray_off[r] = p1;
        if (p1 == PTOT-1) for (int r=rid1[q]+1; r<=NRAYS; ++r) ray_off[r] = PTOT;
    }
    #pragma unroll 2
    for (int i=0;i<128;i++){
        Q2 wd; wd.q = WD4[i];            // lo=(wx,wy)  hi=(wz,bias)
        F2 w2v = WD2v[i];
        #pragma unroll
        for (int q=0;q<4;q++){
            F2 h = pk_fma_lo_chi(pz[q], wd.h.hi, wd.h.hi);   // pz*wz + bias
            h = pk_fma_hi(py[q], wd.h.lo, h);                // + py*wy
            h = pk_fma_lo(px[q], wd.h.lo, h);                // + px*wx
            h = f2relu(h);
            dens[q] = pk_fma_lo(h, w2v, dens[q]);            // += h*w2
        }
    }
    #pragma unroll
    for (int q=0;q<4;q++){
        float a0 = raw2alpha_f(dens[q].x);
        float a1 = raw2alpha_f(dens[q].y);
        alpha0[base + (2*q)*256]   = (a0 > THRESH) ? a0 : 0.f;
        alpha0[base + (2*q+1)*256] = (a1 > THRESH) ? a1 : 0.f;
    }
    // gate: top-2 of softmax over 8 experts, renormalized
    float m0[8], m1[8]; int i0[8], i1[8];
    #pragma unroll
    for (int j=0;j<8;j++){ m0[j]=-3.0e38f; m1[j]=-3.0e38f; i0[j]=0; i1[j]=0; }
    for (int e=0;e<8;e++){
        float w0=WGs[e][0],w1=WGs[e][1],w2=WGs[e][2],w3=WGs[e][3],w4=WGs[e][4],w5=WGs[e][5];
        #pragma unroll
        for (int q=0;q<4;q++){
            F2 l = f2fma(px[q],w0, f2fma(py[q],w1, f2fma(pz[q],w2,
                   f2fma(vx[q],w3, f2fma(vy[q],w4,
                   __builtin_elementwise_fma(vz[q], f2splat(w5), f2splat(0.f)))))));
            int j0 = 2*q, j1 = 2*q+1;
            float lx = l.x, ly = l.y;
            if (lx > m0[j0]){ m1[j0]=m0[j0]; i1[j0]=i0[j0]; m0[j0]=lx; i0[j0]=e; }
            else if (lx > m1[j0]){ m1[j0]=lx; i1[j0]=e; }
            if (ly > m0[j1]){ m1[j1]=m0[j1]; i1[j1]=i0[j1]; m0[j1]=ly; i0[j1]=e; }
            else if (ly > m1[j1]){ m1[j1]=ly; i1[j1]=e; }
        }
    }
    #pragma unroll
    for (int j=0;j<8;j++){
        float g0 = __fdividef(1.0f, 1.0f + __expf(m1[j]-m0[j]));
        g0a[base + j*256] = g0;
        eea[base + j*256] = i0[j] | (i1[j] << 8);
    }
}

// ---------------- kernel 2: transmittance scan -> keep mask + expert counts ----------------
__global__ __launch_bounds__(256) void k_scan0(const float* __restrict__ alpha0,
                                               const int* __restrict__ eea,
                                               const int* __restrict__ ray_off,
                                               unsigned char* __restrict__ keep,
                                               int* __restrict__ cntA)
{
    __shared__ int wcs[4][8];
    int t = threadIdx.x, lane = t & 63, w = t >> 6;
    int wid = blockIdx.x*4 + w;                      // wave = ray
    int c[8];
    #pragma unroll
    for (int e=0;e<8;e++) c[e]=0;
    int s = ray_off[wid], e = ray_off[wid+1];
    float carry = 1.f;
    for (int ch = s; ch < e; ch += 64){
        int p = ch + lane;
        bool in = p < e;
        float a = in ? alpha0[p] : 0.f;
        int  ee = in ? eea[p] : 0;
        float incl = 1.f - a;
        #pragma unroll
        for (int d=1; d<64; d<<=1){ float tt = __shfl_up(incl, d); if (lane >= d) incl *= tt; }
        float excl = __shfl_up(incl, 1); if (lane == 0) excl = 1.f;
        float w0 = a * carry * excl;
        int k = (in && w0 > THRESH) ? 1 : 0;
        if (in) keep[p] = (unsigned char)k;
        int e0 = ee & 255, e1 = (ee >> 8) & 255;
        #pragma unroll
        for (int x=0;x<8;x++){
            unsigned long long m0 = __ballot(k && e0==x);
            unsigned long long m1 = __ballot(k && e1==x);
            c[x] += __popcll(m0) + __popcll(m1);
        }
        carry *= __shfl(incl, 63);
    }
    if (lane == 0){
        #pragma unroll
        for (int x=0;x<8;x++) wcs[w][x] = c[x];
    }
    __syncthreads();
    if (t < 8){
        int sum = wcs[0][t]+wcs[1][t]+wcs[2][t]+wcs[3][t];
        if (sum) atomicAdd(&cntA[t], sum);
    }
}

// ---------------- kernel 3: fill entries (ballot-ranked; local prefix of cntA) ----------------
// entry.x = pid | (slot << 30), entry.y = gate weight bits
__global__ __launch_bounds__(256) void k_fill(const unsigned char* __restrict__ keep,
                                              const float* __restrict__ g0a,
                                              const int* __restrict__ eea,
                                              const int* __restrict__ cntA,
                                              int* __restrict__ curA,
                                              int2* __restrict__ ent)
{
    __shared__ int wc[4][8];
    __shared__ int wb[4][8];
    __shared__ int sOff[8];
    int t = threadIdx.x, lane = t & 63, w = t >> 6;
    unsigned long long lt = (1ull << lane) - 1ull;
    int base = blockIdx.x * 2048;

    int c[8];
    #pragma unroll
    for (int e=0;e<8;e++) c[e]=0;
    for (int j=0;j<8;j++){
        int p = base + (j*4 + w)*64 + lane;
        int k = keep[p];
        int ee = eea[p];
        int e0 = ee & 255, e1 = (ee >> 8) & 255;
        #pragma unroll
        for (int e=0;e<8;e++){
            unsigned long long m0 = __ballot(k && e0==e);
            unsigned long long m1 = __ballot(k && e1==e);
            c[e] += __popcll(m0) + __popcll(m1);
        }
    }
    if (lane == 0){
        #pragma unroll
        for (int e=0;e<8;e++) wc[w][e] = c[e];
    }
    if (t == 0){                                // local exclusive prefix of cntA
        int acc = 0;
        for (int e=0;e<8;e++){ sOff[e] = acc; acc += cntA[e]; }
    }
    __syncthreads();
    if (t < 8){
        int tot = wc[0][t]+wc[1][t]+wc[2][t]+wc[3][t];
        int b = sOff[t] + (tot ? atomicAdd(&curA[t], tot) : 0);
        wb[0][t] = b; b += wc[0][t];
        wb[1][t] = b; b += wc[1][t];
        wb[2][t] = b; b += wc[2][t];
        wb[3][t] = b;
    }
    __syncthreads();

    int cur[8];
    #pragma unroll
    for (int e=0;e<8;e++) cur[e] = wb[w][e];
    for (int j=0;j<8;j++){
        int p = base + (j*4 + w)*64 + lane;
        int k = keep[p];
        float g0 = g0a[p];
        int ee = eea[p];
        int e0 = ee & 255, e1 = (ee >> 8) & 255;
        #pragma unroll
        for (int e=0;e<8;e++){
            unsigned long long m0 = __ballot(k && e0==e);
            unsigned long long m1 = __ballot(k && e1==e);
            if (k && e0==e)
                ent[cur[e] + __popcll(m0 & lt)] = make_int2(p, __float_as_int(g0));
            if (k && e1==e)
                ent[cur[e] + __popcll(m0) + __popcll(m1 & lt)] =
                    make_int2(p | (1 << 30), __float_as_int(1.0f - g0));
            cur[e] += __popcll(m0) + __popcll(m1);
        }
    }
}

// ---------------- kernel 4: expert MLPs (packed-FP32 core, LDS weights) ----------------
// 512 blocks/expert, 256 threads, 4 F2 pairs/thread (proven R0 structure).
// Inner loop forced to v_pk_fma_f32 via inline asm (op_sel broadcasts the scalar weight
// from an aligned LDS float4 half-pair — zero splat cost). 22 -> 12 VALU instr per pair/i.
// NOTE: MFMA variant (prior session) SLOWER (99 vs 91 us). R1 s_load-weights: 127 us.
// R2 packed-32B-entry streams: 92.6 us (not fetch-bound). Scalar F2 baseline: 90.9 us.
__global__ __launch_bounds__(256) void k_expert(
    const int2* __restrict__ ent, const int* __restrict__ cntA,
    const float* __restrict__ pts, const float4* __restrict__ vd,
    const float* __restrict__ We1, const float* __restrict__ be1,
    const float* __restrict__ Wrgb, const float* __restrict__ Walpha,
    float4* __restrict__ res)
{
    int e    = blockIdx.x >> 9;
    int bi   = blockIdx.x & 511;
    int base = bi * 2048;

    __shared__ float4 WA[128];   // We1[e][0..3][i]            lo=(w0,w1) hi=(w2,w3)
    __shared__ float4 WB[128];   // {w4, w5, bias, walpha}     lo=(w4,w5) hi=(bias,walpha)
    __shared__ float4 WC[128];   // {wrgb0, wrgb1, wrgb2, 0}   lo=(r0,r1) hi=(r2,0)
    __shared__ int sSeg[2];      // {segment start, n}
    int t = threadIdx.x;
    if (t < 128){
        const float* w = We1 + e*768;
        WA[t] = make_float4(w[t], w[128+t], w[256+t], w[384+t]);
        WB[t] = make_float4(w[512+t], w[640+t], be1[e*128+t], Walpha[e*128+t]);
        const float* wr = Wrgb + e*384 + 3*t;
        WC[t] = make_float4(wr[0], wr[1], wr[2], 0.f);
    }
    if (t == 0){
        int acc = 0;
        for (int i=0;i<e;i++) acc += cntA[i];
        sSeg[0] = acc; sSeg[1] = cntA[e];
    }
    __syncthreads();
    int n = sSeg[1];
    if (base >= n) return;                      // uniform exit (post-barrier)
    const int2* eb = ent + sSeg[0];

    F2 x0[4],x1[4],x2[4],x3[4],x4[4],x5[4];
    F2 ar[4],ag[4],ab[4],aa[4];
    #pragma unroll
    for (int pr=0;pr<4;pr++){
        int idx0 = base + t + (2*pr)*256, idx1 = idx0 + 256;
        int2 r0 = (idx0 < n) ? eb[idx0] : make_int2(0,0);
        int2 r1 = (idx1 < n) ? eb[idx1] : make_int2(0,0);
        int p0 = r0.x & 0x0FFFFFFF, p1 = r1.x & 0x0FFFFFFF;
        x0[pr] = (F2){pts[3*p0],   pts[3*p1]};
        x1[pr] = (F2){pts[3*p0+1], pts[3*p1+1]};
        x2[pr] = (F2){pts[3*p0+2], pts[3*p1+2]};
        float4 v0 = vd[p0], v1 = vd[p1];
        x3[pr] = (F2){v0.x, v1.x};
        x4[pr] = (F2){v0.y, v1.y};
        x5[pr] = (F2){v0.z, v1.z};
        ar[pr] = f2splat(0.f); ag[pr] = f2splat(0.f);
        ab[pr] = f2splat(0.f); aa[pr] = f2splat(0.f);
    }
    #pragma unroll 2
    for (int i=0;i<128;i++){
        Q2 a, b, c; a.q = WA[i]; b.q = WB[i]; c.q = WC[i];
        #pragma unroll
        for (int pr=0;pr<4;pr++){
            F2 h = pk_fma_hi_clo(x5[pr], b.h.lo, b.h.hi);   // x5*w5 + bias
            h = pk_fma_lo(x4[pr], b.h.lo, h);               // + x4*w4
            h = pk_fma_hi(x3[pr], a.h.hi, h);               // + x3*w3
            h = pk_fma_lo(x2[pr], a.h.hi, h);               // + x2*w2
            h = pk_fma_hi(x1[pr], a.h.lo, h);               // + x1*w1
            h = pk_fma_lo(x0[pr], a.h.lo, h);               // + x0*w0
            h = f2relu(h);
            ar[pr] = pk_fma_lo(h, c.h.lo, ar[pr]);          // += h*wrgb0
            ag[pr] = pk_fma_hi(h, c.h.lo, ag[pr]);          // += h*wrgb1
            ab[pr] = pk_fma_lo(h, c.h.hi, ab[pr]);          // += h*wrgb2
            aa[pr] = pk_fma_hi(h, b.h.hi, aa[pr]);          // += h*walpha
        }
    }
    #pragma unroll
    for (int pr=0;pr<4;pr++){
        #pragma unroll
        for (int sel=0; sel<2; sel++){
            int idx = base + t + (2*pr+sel)*256;
            if (idx < n){
                int2 rec = eb[idx];                 // reload g/pid (keeps loop VGPRs low)
                float vr = sel ? ar[pr].y : ar[pr].x;
                float vg = sel ? ag[pr].y : ag[pr].x;
                float vb = sel ? ab[pr].y : ab[pr].x;
                float va = sel ? aa[pr].y : aa[pr].x;
                float sr = __fdividef(1.0f, 1.0f + __expf(-vr));
                float sg = __fdividef(1.0f, 1.0f + __expf(-vg));
                float sb = __fdividef(1.0f, 1.0f + __expf(-vb));
                float a  = raw2alpha_f(va);
                float g  = __int_as_float(rec.y);
                int pp   = rec.x & 0x0FFFFFFF;
                int slot = ((unsigned)rec.x) >> 30;
                res[2*(size_t)pp + slot] = make_float4(g*sr, g*sg, g*sb, g*a);
            }
        }
    }
}

// ---------------- kernel 5: final per-ray composite ----------------
__global__ __launch_bounds__(256) void k_scan1(const float4* __restrict__ res,
                                               const unsigned char* __restrict__ keep,
                                               const int* __restrict__ ray_off,
                                               const float* __restrict__ bg,
                                               float* __restrict__ out)
{
    int wid  = (blockIdx.x*blockDim.x + threadIdx.x) >> 6;   // wave = ray
    int lane = threadIdx.x & 63;
    if (wid >= NRAYS) return;
    int s = ray_off[wid], e = ray_off[wid+1];
    float carry = 1.f;
    float accx = 0.f, accy = 0.f, accz = 0.f;
    for (int c = s; c < e; c += 64){
        int p = c + lane;
        float4 v = make_float4(0.f,0.f,0.f,0.f);
        if (p < e && keep[p]){
            float4 v0 = res[2*(size_t)p];
            float4 v1 = res[2*(size_t)p + 1];
            v = make_float4(v0.x+v1.x, v0.y+v1.y, v0.z+v1.z, v0.w+v1.w);
        }
        float a = v.w;
        float incl = 1.f - a;
        #pragma unroll
        for (int d=1; d<64; d<<=1){ float tt = __shfl_up(incl, d); if (lane >= d) incl *= tt; }
        float excl = __shfl_up(incl, 1); if (lane == 0) excl = 1.f;
        float w = a * carry * excl;
        accx = fmaf(w, v.x, accx);
        accy = fmaf(w, v.y, accy);
        accz = fmaf(w, v.z, accz);
        carry *= __shfl(incl, 63);
    }
    #pragma unroll
    for (int d=32; d; d>>=1){
        accx += __shfl_xor(accx, d);
        accy += __shfl_xor(accy, d);
        accz += __shfl_xor(accz, d);
    }
    if (lane == 0){
        out[3*wid+0] = accx + carry*bg[0];
        out[3*wid+1] = accy + carry*bg[1];
        out[3*wid+2] = accz + carry*bg[2];
    }
}

extern "C" void kernel_launch(void* const* d_in, const int* in_sizes, int n_in,
                              void* d_out, int out_size, void* d_ws, size_t ws_size,
                              hipStream_t stream)
{
    const float* pts    = (const float*)d_in[0];
    const float* vdirs  = (const float*)d_in[1];
    const float* bg     = (const float*)d_in[2];
    const float* Wd1    = (const float*)d_in[3];
    const float* bd1    = (const float*)d_in[4];
    const float* Wd2    = (const float*)d_in[5];
    const float* Wg     = (const float*)d_in[6];
    const float* We1    = (const float*)d_in[7];
    const float* be1    = (const float*)d_in[8];
    const float* Wrgb   = (const float*)d_in[9];
    const float* Walpha = (const float*)d_in[10];
    const int*   ray_id = (const int*)d_in[11];
    float* out = (float*)d_out;

    char* ws = (char*)d_ws;
    size_t off = 0;
    float* alpha0        = (float*)(ws + off); off += (size_t)PTOT*4;       // 4MB
    float* g0a           = (float*)(ws + off); off += (size_t)PTOT*4;       // 4MB
    int*   eea           = (int*)  (ws + off); off += (size_t)PTOT*4;       // 4MB
    unsigned char* keep  = (unsigned char*)(ws + off); off += (size_t)PTOT; // 1MB
    int*   ray_off       = (int*)  (ws + off); off += 33024;                // 8193+ ints
    int*   cntA          = (int*)  (ws + off); off += 256;
    int*   curA          = (int*)  (ws + off); off += 256;
    off = (off + 255) & ~(size_t)255;
    float4* vd           = (float4*)(ws + off); off += (size_t)PTOT*16;     // 16MB
    int2*  ent           = (int2*) (ws + off); off += (size_t)2*PTOT*8;     // 16MB
    float4* res          = (float4*)(ws + off); off += ((size_t)2*PTOT+2)*16; // 32MB

    hipMemsetAsync(cntA, 0, 512, stream);   // cntA + curA (adjacent)

    k_point <<<PTOT/2048, 256, 0, stream>>>(pts, vdirs, ray_id, Wd1, bd1, Wd2, Wg,
                                            alpha0, g0a, eea, vd, ray_off);
    k_scan0 <<<NRAYS/4, 256, 0, stream>>>(alpha0, eea, ray_off, keep, cntA);
    k_fill  <<<PTOT/2048, 256, 0, stream>>>(keep, g0a, eea, cntA, curA, ent);
    k_expert<<<8*512, 256, 0, stream>>>(ent, cntA, pts, vd,
                                        We1, be1, Wrgb, Walpha, res);
    k_scan1 <<<NRAYS*64/256, 256, 0, stream>>>(res, keep, ray_off, bg, out);
}